// Round 1
// baseline (14185.651 us; speedup 1.0000x reference)
//
#include <hip/hip_runtime.h>

// Problem constants
#define N_TOK 32768
#define DIN   1024
#define HID   512
#define H2    1024   // 2*H
#define KCB   4096
#define NCB   3
#define CHUNK 8192   // token chunk for encoder/decoder hidden activations

// ---------------------------------------------------------------------------
// Generic fp32 tiled GEMM: C[M,Nn] = act(A[M,K] @ B[K,Nn] + bias)
// 64x64 tile, 256 threads, 4x4 per thread, K-tile 16.
// ---------------------------------------------------------------------------
template <bool RELU>
__global__ __launch_bounds__(256) void gemm_bias(
    const float* __restrict__ A, const float* __restrict__ B,
    const float* __restrict__ bias, float* __restrict__ C,
    int M, int K, int Nn) {
  __shared__ float As[64][17];
  __shared__ float Bs[16][64];
  const int tid = threadIdx.x;
  const int tx = tid & 15, ty = tid >> 4;
  const int tx4 = tx * 4, ty4 = ty * 4;
  const int m0 = blockIdx.y * 64, n0 = blockIdx.x * 64;

  const int lm = tid >> 2, lk4 = (tid & 3) * 4;   // A loader: 64 rows x 16 cols
  const int lkb = tid >> 4, ln = (tid & 15) * 4;  // B loader: 16 rows x 64 cols

  float acc[4][4] = {};

  for (int k0 = 0; k0 < K; k0 += 16) {
    float4 av = *(const float4*)(A + (size_t)(m0 + lm) * K + k0 + lk4);
    As[lm][lk4 + 0] = av.x; As[lm][lk4 + 1] = av.y;
    As[lm][lk4 + 2] = av.z; As[lm][lk4 + 3] = av.w;
    *(float4*)(&Bs[lkb][ln]) = *(const float4*)(B + (size_t)(k0 + lkb) * Nn + n0 + ln);
    __syncthreads();
#pragma unroll
    for (int kk = 0; kk < 16; ++kk) {
      float a[4];
#pragma unroll
      for (int i = 0; i < 4; ++i) a[i] = As[ty4 + i][kk];
      float4 b = *(float4*)(&Bs[kk][tx4]);
      float bv[4] = {b.x, b.y, b.z, b.w};
#pragma unroll
      for (int i = 0; i < 4; ++i)
#pragma unroll
        for (int j = 0; j < 4; ++j) acc[i][j] = fmaf(a[i], bv[j], acc[i][j]);
    }
    __syncthreads();
  }

  float bb[4];
#pragma unroll
  for (int j = 0; j < 4; ++j) bb[j] = bias[n0 + tx4 + j];
#pragma unroll
  for (int i = 0; i < 4; ++i) {
#pragma unroll
    for (int j = 0; j < 4; ++j) {
      float v = acc[i][j] + bb[j];
      if (RELU) v = v > 0.0f ? v : 0.0f;
      C[(size_t)(m0 + ty4 + i) * Nn + n0 + tx4 + j] = v;
    }
  }
}

// ---------------------------------------------------------------------------
// Codebook squared norms in f64 (one wave per code, all stages at once)
// ---------------------------------------------------------------------------
__global__ __launch_bounds__(256) void cnorm_kernel(
    const float* __restrict__ cb, double* __restrict__ cn) {
  const int w = blockIdx.x * 4 + (threadIdx.x >> 6);  // code id in [0, NCB*KCB)
  const int lane = threadIdx.x & 63;
  const float* row = cb + (size_t)w * HID;
  double s = 0.0;
  for (int h = lane; h < HID; h += 64) {
    double v = (double)row[h];
    s += v * v;
  }
#pragma unroll
  for (int off = 32; off > 0; off >>= 1) s += __shfl_down(s, off, 64);
  if (lane == 0) cn[w] = s;
}

// ---------------------------------------------------------------------------
// Fused distance + argmin over one codebook stage.
// Block: 64 tokens, loops over code chunks of 64; inner dot over HID.
// d = |c|^2 - 2*(r.c)  (row term |r|^2 dropped: constant per row).
// Final d formed and compared in f64 to kill final-rounding noise.
// Tie-break: smallest index (matches np.argmin first occurrence).
// ---------------------------------------------------------------------------
__global__ __launch_bounds__(256) void rvq_argmin(
    const float* __restrict__ resid, const float* __restrict__ cb,
    const double* __restrict__ cn, int* __restrict__ idxbuf,
    float* __restrict__ idxout) {
  __shared__ float As[64][17];
  __shared__ float Cs[64][17];
  const int tid = threadIdx.x;
  const int tx = tid & 15, ty = tid >> 4;
  const int tx4 = tx * 4, ty4 = ty * 4;
  const int m0 = blockIdx.x * 64;
  const int lm = tid >> 2, lk4 = (tid & 3) * 4;

  double bestD[4];
  int bestI[4];
#pragma unroll
  for (int i = 0; i < 4; ++i) { bestD[i] = 1e300; bestI[i] = 0; }

  for (int kc = 0; kc < KCB; kc += 64) {
    float acc[4][4] = {};
    for (int h0 = 0; h0 < HID; h0 += 16) {
      float4 av = *(const float4*)(resid + (size_t)(m0 + lm) * HID + h0 + lk4);
      As[lm][lk4 + 0] = av.x; As[lm][lk4 + 1] = av.y;
      As[lm][lk4 + 2] = av.z; As[lm][lk4 + 3] = av.w;
      float4 cv = *(const float4*)(cb + (size_t)(kc + lm) * HID + h0 + lk4);
      Cs[lm][lk4 + 0] = cv.x; Cs[lm][lk4 + 1] = cv.y;
      Cs[lm][lk4 + 2] = cv.z; Cs[lm][lk4 + 3] = cv.w;
      __syncthreads();
#pragma unroll
      for (int kk = 0; kk < 16; ++kk) {
        float a[4], c[4];
#pragma unroll
        for (int i = 0; i < 4; ++i) a[i] = As[ty4 + i][kk];
#pragma unroll
        for (int j = 0; j < 4; ++j) c[j] = Cs[tx4 + j][kk];
#pragma unroll
        for (int i = 0; i < 4; ++i)
#pragma unroll
          for (int j = 0; j < 4; ++j) acc[i][j] = fmaf(a[i], c[j], acc[i][j]);
      }
      __syncthreads();
    }
#pragma unroll
    for (int j = 0; j < 4; ++j) {
      const int code = kc + tx4 + j;
      const double cnj = cn[code];
#pragma unroll
      for (int i = 0; i < 4; ++i) {
        double d = cnj - 2.0 * (double)acc[i][j];
        if (d < bestD[i] || (d == bestD[i] && code < bestI[i])) {
          bestD[i] = d; bestI[i] = code;
        }
      }
    }
  }

  // cross-thread (tx) reduction per token
  __shared__ double redD[64][17];
  __shared__ int redI[64][17];
#pragma unroll
  for (int i = 0; i < 4; ++i) {
    redD[ty4 + i][tx] = bestD[i];
    redI[ty4 + i][tx] = bestI[i];
  }
  __syncthreads();
  if (tid < 64) {
    double bd = redD[tid][0];
    int bi = redI[tid][0];
#pragma unroll
    for (int t = 1; t < 16; ++t) {
      double d = redD[tid][t];
      int ii = redI[tid][t];
      if (d < bd || (d == bd && ii < bi)) { bd = d; bi = ii; }
    }
    idxbuf[m0 + tid] = bi;
    idxout[m0 + tid] = (float)bi;
  }
}

// ---------------------------------------------------------------------------
// Gather selected code rows; quantized += sel; residual -= sel.
// One thread per float4 of (token, h).
// ---------------------------------------------------------------------------
__global__ __launch_bounds__(256) void rvq_update(
    const float* __restrict__ cb, const int* __restrict__ idxbuf,
    float* __restrict__ quant, float* __restrict__ resid) {
  const size_t gid = (size_t)blockIdx.x * blockDim.x + threadIdx.x;  // N_TOK*128
  const int t = (int)(gid >> 7);
  const int q = (int)(gid & 127);
  const int idx = idxbuf[t];
  const float4 c = *((const float4*)(cb + (size_t)idx * HID) + q);
  float4* qp = (float4*)(quant + (size_t)t * HID) + q;
  float4* rp = (float4*)(resid + (size_t)t * HID) + q;
  float4 qv = *qp, rv = *rp;
  qv.x += c.x; qv.y += c.y; qv.z += c.z; qv.w += c.w;
  rv.x -= c.x; rv.y -= c.y; rv.z -= c.z; rv.w -= c.w;
  *qp = qv;
  *rp = rv;
}

// ---------------------------------------------------------------------------
extern "C" void kernel_launch(void* const* d_in, const int* in_sizes, int n_in,
                              void* d_out, int out_size, void* d_ws, size_t ws_size,
                              hipStream_t stream) {
  const float* x      = (const float*)d_in[0];
  const float* enc_w1 = (const float*)d_in[1];
  const float* enc_b1 = (const float*)d_in[2];
  const float* enc_w2 = (const float*)d_in[3];
  const float* enc_b2 = (const float*)d_in[4];
  const float* dec_w1 = (const float*)d_in[5];
  const float* dec_b1 = (const float*)d_in[6];
  const float* dec_w2 = (const float*)d_in[7];
  const float* dec_b2 = (const float*)d_in[8];
  const float* cbs    = (const float*)d_in[9];

  float* quant  = (float*)d_out;                       // [N_TOK, HID]
  float* idxout = quant + (size_t)N_TOK * HID;         // [NCB, N_TOK] as float
  float* recon  = idxout + (size_t)NCB * N_TOK;        // [N_TOK, DIN]

  // workspace layout (~101.2 MB total)
  char* w = (char*)d_ws;
  float* resid = (float*)w;            w += (size_t)N_TOK * HID * 4;     // 67.1 MB
  float* a1    = (float*)w;            w += (size_t)CHUNK * H2 * 4;      // 33.6 MB
  int*   idxbuf = (int*)w;             w += (size_t)NCB * N_TOK * 4;     // 0.39 MB
  double* cn   = (double*)w;           w += (size_t)NCB * KCB * 8;       // 0.10 MB

  // codebook norms (f64), all stages
  cnorm_kernel<<<NCB * KCB / 4, 256, 0, stream>>>(cbs, cn);

  // encoder: h = relu(x@W1+b1)@W2+b2 -> resid
  for (int c = 0; c < N_TOK / CHUNK; ++c) {
    gemm_bias<true><<<dim3(H2 / 64, CHUNK / 64), 256, 0, stream>>>(
        x + (size_t)c * CHUNK * DIN, enc_w1, enc_b1, a1, CHUNK, DIN, H2);
    gemm_bias<false><<<dim3(HID / 64, CHUNK / 64), 256, 0, stream>>>(
        a1, enc_w2, enc_b2, resid + (size_t)c * CHUNK * HID, CHUNK, H2, HID);
  }

  // quantized starts at zero
  hipMemsetAsync(d_out, 0, (size_t)N_TOK * HID * 4, stream);

  // RVQ stages
  for (int s = 0; s < NCB; ++s) {
    const float* cb = cbs + (size_t)s * KCB * HID;
    rvq_argmin<<<N_TOK / 64, 256, 0, stream>>>(
        resid, cb, cn + (size_t)s * KCB, idxbuf + (size_t)s * N_TOK,
        idxout + (size_t)s * N_TOK);
    rvq_update<<<(N_TOK * 128) / 256, 256, 0, stream>>>(
        cb, idxbuf + (size_t)s * N_TOK, quant, resid);
  }

  // decoder: recon = relu(q@W1+b1)@W2+b2
  for (int c = 0; c < N_TOK / CHUNK; ++c) {
    gemm_bias<true><<<dim3(H2 / 64, CHUNK / 64), 256, 0, stream>>>(
        quant + (size_t)c * CHUNK * HID, dec_w1, dec_b1, a1, CHUNK, HID, H2);
    gemm_bias<false><<<dim3(DIN / 64, CHUNK / 64), 256, 0, stream>>>(
        a1, dec_w2, dec_b2, recon + (size_t)c * CHUNK * DIN, CHUNK, H2, DIN);
  }
}

// Round 3
// 5883.781 us; speedup vs baseline: 2.4110x; 2.4110x over previous
//
#include <hip/hip_runtime.h>

#define N_TOK 32768
#define DIN   1024
#define HID   512
#define H2    1024
#define KCB   4096
#define NCB   3
#define CHUNK 2048

typedef _Float16 f16x8 __attribute__((ext_vector_type(8)));
typedef float f32x4 __attribute__((ext_vector_type(4)));
typedef unsigned short u16;

__device__ inline u16 f2h_bits(float v) {
  union { _Float16 f; u16 u; } cv;
  cv.f = (_Float16)v;
  return cv.u;
}
__device__ inline float h_bits2f(u16 u) {
  union { _Float16 f; u16 u; } cv;
  cv.u = u;
  return (float)cv.f;
}
// split v = hi + (lo/2048); lo stored pre-scaled by 2048 (avoids f16 subnormals)
__device__ inline void fsplit(float v, u16& hi, u16& lo) {
  _Float16 h = (_Float16)v;
  float hf = (float)h;
  union { _Float16 f; u16 u; } ch; ch.f = h; hi = ch.u;
  lo = f2h_bits((v - hf) * 2048.0f);
}

// ---------------------------------------------------------------------------
// fp32 tiled GEMM: C = act(A@B + bias). 64x64 tile, 256 thr, 4x4/thread.
// SPLIT: write f16 hi/lo planes instead of f32 C (for enc2 -> resid splits).
// ---------------------------------------------------------------------------
template <bool RELU, bool SPLIT>
__global__ __launch_bounds__(256) void gemm_bias(
    const float* __restrict__ A, const float* __restrict__ B,
    const float* __restrict__ bias, float* __restrict__ C,
    u16* __restrict__ Chi, u16* __restrict__ Clo,
    int M, int K, int Nn) {
  __shared__ float As[64][17];
  __shared__ float Bs[16][64];
  const int tid = threadIdx.x;
  const int tx = tid & 15, ty = tid >> 4;
  const int tx4 = tx * 4, ty4 = ty * 4;
  const int m0 = blockIdx.y * 64, n0 = blockIdx.x * 64;
  const int lm = tid >> 2, lk4 = (tid & 3) * 4;
  const int lkb = tid >> 4, ln = (tid & 15) * 4;

  float acc[4][4] = {};

  for (int k0 = 0; k0 < K; k0 += 16) {
    float4 av = *(const float4*)(A + (size_t)(m0 + lm) * K + k0 + lk4);
    As[lm][lk4 + 0] = av.x; As[lm][lk4 + 1] = av.y;
    As[lm][lk4 + 2] = av.z; As[lm][lk4 + 3] = av.w;
    *(float4*)(&Bs[lkb][ln]) = *(const float4*)(B + (size_t)(k0 + lkb) * Nn + n0 + ln);
    __syncthreads();
#pragma unroll
    for (int kk = 0; kk < 16; ++kk) {
      float a[4];
#pragma unroll
      for (int i = 0; i < 4; ++i) a[i] = As[ty4 + i][kk];
      float4 b = *(float4*)(&Bs[kk][tx4]);
      float bv[4] = {b.x, b.y, b.z, b.w};
#pragma unroll
      for (int i = 0; i < 4; ++i)
#pragma unroll
        for (int j = 0; j < 4; ++j) acc[i][j] = fmaf(a[i], bv[j], acc[i][j]);
    }
    __syncthreads();
  }

  float bb[4];
#pragma unroll
  for (int j = 0; j < 4; ++j) bb[j] = bias[n0 + tx4 + j];
#pragma unroll
  for (int i = 0; i < 4; ++i) {
    if (SPLIT) {
      ushort4 h4, l4;
      u16 hs[4], ls[4];
#pragma unroll
      for (int j = 0; j < 4; ++j) {
        float v = acc[i][j] + bb[j];
        if (RELU) v = v > 0.0f ? v : 0.0f;
        fsplit(v, hs[j], ls[j]);
      }
      h4.x = hs[0]; h4.y = hs[1]; h4.z = hs[2]; h4.w = hs[3];
      l4.x = ls[0]; l4.y = ls[1]; l4.z = ls[2]; l4.w = ls[3];
      *(ushort4*)(&Chi[(size_t)(m0 + ty4 + i) * Nn + n0 + tx4]) = h4;
      *(ushort4*)(&Clo[(size_t)(m0 + ty4 + i) * Nn + n0 + tx4]) = l4;
    } else {
#pragma unroll
      for (int j = 0; j < 4; ++j) {
        float v = acc[i][j] + bb[j];
        if (RELU) v = v > 0.0f ? v : 0.0f;
        C[(size_t)(m0 + ty4 + i) * Nn + n0 + tx4 + j] = v;
      }
    }
  }
}

// ---------------------------------------------------------------------------
// Split all codebooks fp32 -> f16 hi/lo planes (lo pre-scaled 2048).
// ---------------------------------------------------------------------------
__global__ __launch_bounds__(256) void cbsplit_kernel(
    const float* __restrict__ cb, u16* __restrict__ hi, u16* __restrict__ lo) {
  const size_t i4 = (size_t)blockIdx.x * 256 + threadIdx.x;
  float4 v = *(const float4*)(cb + i4 * 4);
  ushort4 h4, l4;
  fsplit(v.x, h4.x, l4.x);
  fsplit(v.y, h4.y, l4.y);
  fsplit(v.z, h4.z, l4.z);
  fsplit(v.w, h4.w, l4.w);
  *(ushort4*)(hi + i4 * 4) = h4;
  *(ushort4*)(lo + i4 * 4) = l4;
}

// ---------------------------------------------------------------------------
// Codebook squared norms in f64 (one wave per code, all stages at once)
// ---------------------------------------------------------------------------
__global__ __launch_bounds__(256) void cnorm_kernel(
    const float* __restrict__ cb, double* __restrict__ cn) {
  const int w = blockIdx.x * 4 + (threadIdx.x >> 6);
  const int lane = threadIdx.x & 63;
  const float* row = cb + (size_t)w * HID;
  double s = 0.0;
  for (int h = lane; h < HID; h += 64) {
    double v = (double)row[h];
    s += v * v;
  }
#pragma unroll
  for (int off = 32; off > 0; off >>= 1) s += __shfl_down(s, off, 64);
  if (lane == 0) cn[w] = s;
}

// ---------------------------------------------------------------------------
// MFMA argmin: d = |c|^2 - 2*r.c with r,c in 2-term f16 splits (3 products).
// Block: 4 waves, 64 tokens x 128-code chunks. Wave: 32 tokens x 64 codes.
// Staging: global_load_lds (16B) with pre-swizzled source (slot ^ (row>>1)&3).
// Final d formed & compared in f64 (round-1 precision protocol): kills the
// ulp(512)=6e-5 final-rounding noise that flipped near-tie argmins in r2.
// ---------------------------------------------------------------------------
#define SWZ(r) (((r) >> 1) & 3)

__device__ inline void stage16(const u16* gplane, int growbase, int lrowbase,
                               int k0, u16* ldsbase, int l) {
  const int rp = l >> 2, s = l & 3;
  const int lrow = lrowbase + rp;
  const int sp = s ^ SWZ(lrow);
  const u16* src = gplane + (size_t)(growbase + rp) * HID + k0 + sp * 8;
  __builtin_amdgcn_global_load_lds(
      (const __attribute__((address_space(1))) void*)src,
      (__attribute__((address_space(3))) void*)ldsbase, 16, 0, 0);
}

__global__ __launch_bounds__(256) void rvq_argmin_mfma(
    const u16* __restrict__ Ahi, const u16* __restrict__ Alo,
    const u16* __restrict__ Bhi, const u16* __restrict__ Blo,
    const double* __restrict__ cn, int* __restrict__ idxbuf,
    float* __restrict__ idxout) {
  __shared__ __attribute__((aligned(16))) u16 As[2 * 64 * 32];    // 8 KB
  __shared__ __attribute__((aligned(16))) u16 Bs[2 * 128 * 32];   // 16 KB
  __shared__ double mergeD[128];
  __shared__ int mergeI[128];

  const int tid = threadIdx.x;
  const int w = tid >> 6, l = tid & 63;
  const int wr = w >> 1, wc = w & 1;
  const int lr = l & 15, g = l >> 4;
  const int m0 = blockIdx.x * 64;

  double bestD[2][4];
  int bestI[2][4];
#pragma unroll
  for (int mr = 0; mr < 2; ++mr)
#pragma unroll
    for (int q = 0; q < 4; ++q) { bestD[mr][q] = 1e300; bestI[mr][q] = 0; }

  for (int chunk = 0; chunk < KCB / 128; ++chunk) {
    const int cbase = chunk * 128;
    f32x4 acch[2][4], accc[2][4];
#pragma unroll
    for (int mr = 0; mr < 2; ++mr)
#pragma unroll
      for (int nr = 0; nr < 4; ++nr) {
        acch[mr][nr] = (f32x4)0.0f;
        accc[mr][nr] = (f32x4)0.0f;
      }

    for (int ks = 0; ks < HID / 32; ++ks) {
      const int k0 = ks * 32;
      __syncthreads();
      // stage A (64 rows x 2 planes) + B (128 rows x 2 planes)
      stage16(Ahi, m0 + w * 16, w * 16, k0, As + w * 16 * 32, l);
      stage16(Alo, m0 + w * 16, w * 16, k0, As + 2048 + w * 16 * 32, l);
      stage16(Bhi, cbase + w * 16, w * 16, k0, Bs + w * 16 * 32, l);
      stage16(Bhi, cbase + (w + 4) * 16, (w + 4) * 16, k0, Bs + (w + 4) * 16 * 32, l);
      stage16(Blo, cbase + w * 16, w * 16, k0, Bs + 4096 + w * 16 * 32, l);
      stage16(Blo, cbase + (w + 4) * 16, (w + 4) * 16, k0, Bs + 4096 + (w + 4) * 16 * 32, l);
      __syncthreads();

      f16x8 ah[2], al[2], bh[4], bl[4];
#pragma unroll
      for (int mr = 0; mr < 2; ++mr) {
        const int ra = wr * 32 + mr * 16 + lr;
        const int pa = (g ^ SWZ(ra)) * 8;
        ah[mr] = *(const f16x8*)(As + ra * 32 + pa);
        al[mr] = *(const f16x8*)(As + 2048 + ra * 32 + pa);
      }
#pragma unroll
      for (int nr = 0; nr < 4; ++nr) {
        const int rb = wc * 64 + nr * 16 + lr;
        const int pb = (g ^ SWZ(rb)) * 8;
        bh[nr] = *(const f16x8*)(Bs + rb * 32 + pb);
        bl[nr] = *(const f16x8*)(Bs + 4096 + rb * 32 + pb);
      }
#pragma unroll
      for (int mr = 0; mr < 2; ++mr)
#pragma unroll
        for (int nr = 0; nr < 4; ++nr) {
          acch[mr][nr] = __builtin_amdgcn_mfma_f32_16x16x32_f16(
              ah[mr], bh[nr], acch[mr][nr], 0, 0, 0);
          accc[mr][nr] = __builtin_amdgcn_mfma_f32_16x16x32_f16(
              ah[mr], bl[nr], accc[mr][nr], 0, 0, 0);
          accc[mr][nr] = __builtin_amdgcn_mfma_f32_16x16x32_f16(
              al[mr], bh[nr], accc[mr][nr], 0, 0, 0);
        }
    }

    // epilogue (f64): d = cn - 2*acch - (2/2048)*accc ; running argmin
#pragma unroll
    for (int nr = 0; nr < 4; ++nr) {
      const int code = cbase + wc * 64 + nr * 16 + lr;
      const double cnj = cn[code];
#pragma unroll
      for (int mr = 0; mr < 2; ++mr) {
#pragma unroll
        for (int q = 0; q < 4; ++q) {
          double d = cnj - 2.0 * (double)acch[mr][nr][q]
                         - 9.765625e-4 * (double)accc[mr][nr][q];
          if (d < bestD[mr][q]) { bestD[mr][q] = d; bestI[mr][q] = code; }
        }
      }
    }
  }

  // reduce across the 16 lanes (lr) of each g-group
#pragma unroll
  for (int mr = 0; mr < 2; ++mr) {
#pragma unroll
    for (int q = 0; q < 4; ++q) {
      double d = bestD[mr][q];
      int i = bestI[mr][q];
#pragma unroll
      for (int off = 1; off < 16; off <<= 1) {
        double od = __shfl_xor(d, off, 64);
        int oi = __shfl_xor(i, off, 64);
        if (od < d || (od == d && oi < i)) { d = od; i = oi; }
      }
      if (lr == 0) {
        const int tl = wr * 32 + mr * 16 + 4 * g + q;
        mergeD[tl * 2 + wc] = d;
        mergeI[tl * 2 + wc] = i;
      }
    }
  }
  __syncthreads();
  if (tid < 64) {
    double d0 = mergeD[tid * 2], d1 = mergeD[tid * 2 + 1];
    int i0 = mergeI[tid * 2], i1 = mergeI[tid * 2 + 1];
    if (d1 < d0 || (d1 == d0 && i1 < i0)) { d0 = d1; i0 = i1; }
    idxbuf[m0 + tid] = i0;
    idxout[m0 + tid] = (float)i0;
  }
}

// ---------------------------------------------------------------------------
// Gather sel; quant += sel; resid(split) -= sel; re-split residual.
// ---------------------------------------------------------------------------
__global__ __launch_bounds__(256) void rvq_update(
    const float* __restrict__ cb, const int* __restrict__ idxbuf,
    float* __restrict__ quant, u16* __restrict__ rhi, u16* __restrict__ rlo) {
  const size_t gid = (size_t)blockIdx.x * blockDim.x + threadIdx.x;  // N_TOK*128
  const int t = (int)(gid >> 7);
  const int q4 = (int)(gid & 127);
  const int idx = idxbuf[t];
  const float4 c = *((const float4*)(cb + (size_t)idx * HID) + q4);
  float4* qp = (float4*)(quant + (size_t)t * HID) + q4;
  float4 qv = *qp;
  ushort4* hp = (ushort4*)(rhi + (size_t)t * HID) + q4;
  ushort4* lp = (ushort4*)(rlo + (size_t)t * HID) + q4;
  ushort4 h4 = *hp, l4 = *lp;
  float r[4], cc[4] = {c.x, c.y, c.z, c.w};
  u16 hs[4] = {h4.x, h4.y, h4.z, h4.w}, ls[4] = {l4.x, l4.y, l4.z, l4.w};
#pragma unroll
  for (int j = 0; j < 4; ++j) {
    r[j] = h_bits2f(hs[j]) + h_bits2f(ls[j]) * (1.0f / 2048.0f) - cc[j];
    fsplit(r[j], hs[j], ls[j]);
  }
  qv.x += c.x; qv.y += c.y; qv.z += c.z; qv.w += c.w;
  *qp = qv;
  h4.x = hs[0]; h4.y = hs[1]; h4.z = hs[2]; h4.w = hs[3];
  l4.x = ls[0]; l4.y = ls[1]; l4.z = ls[2]; l4.w = ls[3];
  *hp = h4;
  *lp = l4;
}

// ---------------------------------------------------------------------------
extern "C" void kernel_launch(void* const* d_in, const int* in_sizes, int n_in,
                              void* d_out, int out_size, void* d_ws, size_t ws_size,
                              hipStream_t stream) {
  const float* x      = (const float*)d_in[0];
  const float* enc_w1 = (const float*)d_in[1];
  const float* enc_b1 = (const float*)d_in[2];
  const float* enc_w2 = (const float*)d_in[3];
  const float* enc_b2 = (const float*)d_in[4];
  const float* dec_w1 = (const float*)d_in[5];
  const float* dec_b1 = (const float*)d_in[6];
  const float* dec_w2 = (const float*)d_in[7];
  const float* dec_b2 = (const float*)d_in[8];
  const float* cbs    = (const float*)d_in[9];

  float* quant  = (float*)d_out;                // [N_TOK, HID]
  float* idxout = quant + (size_t)N_TOK * HID;  // [NCB, N_TOK] as float
  float* recon  = idxout + (size_t)NCB * N_TOK; // [N_TOK, DIN]

  // workspace (~101.1 MB)
  char* w = (char*)d_ws;
  float* a1  = (float*)w;  w += (size_t)CHUNK * H2 * 4;          // 8.39 MB
  u16* rhi   = (u16*)w;    w += (size_t)N_TOK * HID * 2;         // 33.55 MB
  u16* rlo   = (u16*)w;    w += (size_t)N_TOK * HID * 2;         // 33.55 MB
  u16* cbhi  = (u16*)w;    w += (size_t)NCB * KCB * HID * 2;     // 12.58 MB
  u16* cblo  = (u16*)w;    w += (size_t)NCB * KCB * HID * 2;     // 12.58 MB
  int* idxbuf = (int*)w;   w += (size_t)NCB * N_TOK * 4;         // 0.39 MB
  double* cn = (double*)w; w += (size_t)NCB * KCB * 8;           // 0.10 MB

  cbsplit_kernel<<<(NCB * KCB * HID / 4) / 256, 256, 0, stream>>>(cbs, cbhi, cblo);
  cnorm_kernel<<<NCB * KCB / 4, 256, 0, stream>>>(cbs, cn);

  // encoder -> resid splits
  for (int c = 0; c < N_TOK / CHUNK; ++c) {
    gemm_bias<true, false><<<dim3(H2 / 64, CHUNK / 64), 256, 0, stream>>>(
        x + (size_t)c * CHUNK * DIN, enc_w1, enc_b1, a1, nullptr, nullptr,
        CHUNK, DIN, H2);
    gemm_bias<false, true><<<dim3(HID / 64, CHUNK / 64), 256, 0, stream>>>(
        a1, enc_w2, enc_b2, nullptr,
        rhi + (size_t)c * CHUNK * HID, rlo + (size_t)c * CHUNK * HID,
        CHUNK, H2, HID);
  }

  hipMemsetAsync(d_out, 0, (size_t)N_TOK * HID * 4, stream);

  for (int s = 0; s < NCB; ++s) {
    const float* cb = cbs + (size_t)s * KCB * HID;
    rvq_argmin_mfma<<<N_TOK / 64, 256, 0, stream>>>(
        rhi, rlo, cbhi + (size_t)s * KCB * HID, cblo + (size_t)s * KCB * HID,
        cn + (size_t)s * KCB, idxbuf + (size_t)s * N_TOK,
        idxout + (size_t)s * N_TOK);
    rvq_update<<<(N_TOK * 128) / 256, 256, 0, stream>>>(
        cb, idxbuf + (size_t)s * N_TOK, quant, rhi, rlo);
  }

  // decoder
  for (int c = 0; c < N_TOK / CHUNK; ++c) {
    gemm_bias<true, false><<<dim3(H2 / 64, CHUNK / 64), 256, 0, stream>>>(
        quant + (size_t)c * CHUNK * HID, dec_w1, dec_b1, a1, nullptr, nullptr,
        CHUNK, HID, H2);
    gemm_bias<false, false><<<dim3(DIN / 64, CHUNK / 64), 256, 0, stream>>>(
        a1, dec_w2, dec_b2, recon + (size_t)c * CHUNK * DIN, nullptr, nullptr,
        CHUNK, H2, DIN);
  }
}

// Round 5
// 3618.228 us; speedup vs baseline: 3.9206x; 1.6261x over previous
//
#include <hip/hip_runtime.h>

#define N_TOK 32768
#define DIN   1024
#define HID   512
#define H2    1024
#define KCB   4096
#define NCB   3
#define CHUNK_E 4096   // encoder token chunk (h1 f32 buffer bound)
#define CHUNK_D 8192   // decoder token chunk (h1 f16 buffer bound)

typedef _Float16 f16x8 __attribute__((ext_vector_type(8)));
typedef float f32x4 __attribute__((ext_vector_type(4)));
typedef unsigned short u16;

__device__ inline u16 f2h_bits(float v) {
  union { _Float16 f; u16 u; } cv;
  cv.f = (_Float16)v;
  return cv.u;
}
__device__ inline float h_bits2f(u16 u) {
  union { _Float16 f; u16 u; } cv;
  cv.u = u;
  return (float)cv.f;
}
// split v = hi + (lo/2048); lo stored pre-scaled by 2048 (avoids f16 subnormals)
__device__ inline void fsplit(float v, u16& hi, u16& lo) {
  _Float16 h = (_Float16)v;
  float hf = (float)h;
  union { _Float16 f; u16 u; } ch; ch.f = h; hi = ch.u;
  lo = f2h_bits((v - hf) * 2048.0f);
}

#define SWZ(r) (((r) >> 1) & 3)

// global_load_lds 16B stager: 16 rows x 32 u16, pre-swizzled source columns.
__device__ inline void stage16(const u16* gplane, int growbase, int lrowbase,
                               int k0, u16* ldsbase, int l, int stride) {
  const int rp = l >> 2, s = l & 3;
  const int sp = s ^ SWZ(lrowbase + rp);
  const u16* src = gplane + (size_t)(growbase + rp) * stride + k0 + sp * 8;
  __builtin_amdgcn_global_load_lds(
      (const __attribute__((address_space(1))) void*)src,
      (__attribute__((address_space(3))) void*)ldsbase, 16, 0, 0);
}

// ---------------------------------------------------------------------------
// fp32 tiled GEMM — THE index-critical path (enc1, enc2). Numerically
// identical to the round-1/round-3 kernel that passes. DO NOT PERTURB:
// the argmin sits on ~1e-5 distance margins vs the np reference.
// SPLIT epilogue writes f16 hi/lo planes (residual splits).
// ---------------------------------------------------------------------------
template <bool RELU, bool SPLIT>
__global__ __launch_bounds__(256) void gemm_bias(
    const float* __restrict__ A, const float* __restrict__ B,
    const float* __restrict__ bias, float* __restrict__ C,
    u16* __restrict__ Chi, u16* __restrict__ Clo,
    int M, int K, int Nn) {
  __shared__ float As[64][17];
  __shared__ float Bs[16][64];
  const int tid = threadIdx.x;
  const int tx = tid & 15, ty = tid >> 4;
  const int tx4 = tx * 4, ty4 = ty * 4;
  const int m0 = blockIdx.y * 64, n0 = blockIdx.x * 64;
  const int lm = tid >> 2, lk4 = (tid & 3) * 4;
  const int lkb = tid >> 4, ln = (tid & 15) * 4;

  float acc[4][4] = {};

  for (int k0 = 0; k0 < K; k0 += 16) {
    float4 av = *(const float4*)(A + (size_t)(m0 + lm) * K + k0 + lk4);
    As[lm][lk4 + 0] = av.x; As[lm][lk4 + 1] = av.y;
    As[lm][lk4 + 2] = av.z; As[lm][lk4 + 3] = av.w;
    *(float4*)(&Bs[lkb][ln]) = *(const float4*)(B + (size_t)(k0 + lkb) * Nn + n0 + ln);
    __syncthreads();
#pragma unroll
    for (int kk = 0; kk < 16; ++kk) {
      float a[4];
#pragma unroll
      for (int i = 0; i < 4; ++i) a[i] = As[ty4 + i][kk];
      float4 b = *(float4*)(&Bs[kk][tx4]);
      float bv[4] = {b.x, b.y, b.z, b.w};
#pragma unroll
      for (int i = 0; i < 4; ++i)
#pragma unroll
        for (int j = 0; j < 4; ++j) acc[i][j] = fmaf(a[i], bv[j], acc[i][j]);
    }
    __syncthreads();
  }

  float bb[4];
#pragma unroll
  for (int j = 0; j < 4; ++j) bb[j] = bias[n0 + tx4 + j];
#pragma unroll
  for (int i = 0; i < 4; ++i) {
    if (SPLIT) {
      ushort4 h4, l4;
      u16 hs[4], ls[4];
#pragma unroll
      for (int j = 0; j < 4; ++j) {
        float v = acc[i][j] + bb[j];
        if (RELU) v = v > 0.0f ? v : 0.0f;
        fsplit(v, hs[j], ls[j]);
      }
      h4.x = hs[0]; h4.y = hs[1]; h4.z = hs[2]; h4.w = hs[3];
      l4.x = ls[0]; l4.y = ls[1]; l4.z = ls[2]; l4.w = ls[3];
      *(ushort4*)(&Chi[(size_t)(m0 + ty4 + i) * Nn + n0 + tx4]) = h4;
      *(ushort4*)(&Clo[(size_t)(m0 + ty4 + i) * Nn + n0 + tx4]) = l4;
    } else {
#pragma unroll
      for (int j = 0; j < 4; ++j) {
        float v = acc[i][j] + bb[j];
        if (RELU) v = v > 0.0f ? v : 0.0f;
        C[(size_t)(m0 + ty4 + i) * Nn + n0 + tx4 + j] = v;
      }
    }
  }
}

// ---------------------------------------------------------------------------
// Single-product f16 MFMA GEMM (decoder only — recon tolerance ~100x margin).
// A[M,K] (f16 hi plane) x BT[N,K] (f16 hi plane) -> C[M,N] (+bias, relu).
// Block: 4 waves, 64 M x 128 N; wave 32x64; K-step 32. LDS 12 KB.
// ---------------------------------------------------------------------------
template <bool RELU, bool F16OUT>
__global__ __launch_bounds__(256) void gemm_mfma_f16(
    const u16* __restrict__ Ahi, const u16* __restrict__ BThi,
    const float* __restrict__ bias,
    float* __restrict__ C, u16* __restrict__ Chi,
    int M, int K, int Nn) {
  __shared__ __attribute__((aligned(16))) u16 As[64 * 32];    // 4 KB
  __shared__ __attribute__((aligned(16))) u16 Bs[128 * 32];   // 8 KB
  const int tid = threadIdx.x;
  const int w = tid >> 6, l = tid & 63;
  const int wr = w >> 1, wc = w & 1;
  const int lr = l & 15, g = l >> 4;
  const int m0 = blockIdx.y * 64, n0 = blockIdx.x * 128;

  f32x4 acc[2][4];
#pragma unroll
  for (int mr = 0; mr < 2; ++mr)
#pragma unroll
    for (int nr = 0; nr < 4; ++nr) acc[mr][nr] = (f32x4)0.0f;

  for (int ks = 0; ks < K / 32; ++ks) {
    const int k0 = ks * 32;
    __syncthreads();
    stage16(Ahi, m0 + w * 16, w * 16, k0, As + w * 16 * 32, l, K);
    stage16(BThi, n0 + w * 16, w * 16, k0, Bs + w * 16 * 32, l, K);
    stage16(BThi, n0 + (w + 4) * 16, (w + 4) * 16, k0, Bs + (w + 4) * 16 * 32, l, K);
    __syncthreads();

    f16x8 ah[2], bh[4];
#pragma unroll
    for (int mr = 0; mr < 2; ++mr) {
      const int ra = wr * 32 + mr * 16 + lr;
      ah[mr] = *(const f16x8*)(As + ra * 32 + (g ^ SWZ(ra)) * 8);
    }
#pragma unroll
    for (int nr = 0; nr < 4; ++nr) {
      const int rb = wc * 64 + nr * 16 + lr;
      bh[nr] = *(const f16x8*)(Bs + rb * 32 + (g ^ SWZ(rb)) * 8);
    }
#pragma unroll
    for (int mr = 0; mr < 2; ++mr)
#pragma unroll
      for (int nr = 0; nr < 4; ++nr)
        acc[mr][nr] = __builtin_amdgcn_mfma_f32_16x16x32_f16(
            ah[mr], bh[nr], acc[mr][nr], 0, 0, 0);
  }

#pragma unroll
  for (int nr = 0; nr < 4; ++nr) {
    const int col = n0 + wc * 64 + nr * 16 + lr;
    const float bb = bias[col];
#pragma unroll
    for (int mr = 0; mr < 2; ++mr) {
#pragma unroll
      for (int q = 0; q < 4; ++q) {
        const int row = m0 + wr * 32 + mr * 16 + g * 4 + q;
        float v = acc[mr][nr][q] + bb;
        if (RELU) v = v > 0.0f ? v : 0.0f;
        if (F16OUT) Chi[(size_t)row * Nn + col] = f2h_bits(v);
        else C[(size_t)row * Nn + col] = v;
      }
    }
  }
}

// ---------------------------------------------------------------------------
// Weight transpose + split: W[K][N] -> Thi/Tlo[N][K].
// ---------------------------------------------------------------------------
__global__ __launch_bounds__(256) void wtsplit(
    const float* __restrict__ W, u16* __restrict__ Thi, u16* __restrict__ Tlo,
    int K, int N) {
  __shared__ float tile[32][33];
  const int k0 = blockIdx.y * 32, n0 = blockIdx.x * 32;
  const int c = threadIdx.x & 31, r8 = threadIdx.x >> 5;
#pragma unroll
  for (int p = 0; p < 4; ++p) {
    const int r = r8 + p * 8;
    tile[r][c] = W[(size_t)(k0 + r) * N + n0 + c];
  }
  __syncthreads();
#pragma unroll
  for (int p = 0; p < 4; ++p) {
    const int r = r8 + p * 8;
    float v = tile[c][r];
    u16 hh, ll;
    fsplit(v, hh, ll);
    Thi[(size_t)(n0 + r) * K + k0 + c] = hh;
    Tlo[(size_t)(n0 + r) * K + k0 + c] = ll;
  }
}

// ---------------------------------------------------------------------------
// Codebook split (one stage) fp32 -> f16 hi/lo planes.
// ---------------------------------------------------------------------------
__global__ __launch_bounds__(256) void cbsplit_kernel(
    const float* __restrict__ cb, u16* __restrict__ hi, u16* __restrict__ lo) {
  const size_t i4 = (size_t)blockIdx.x * 256 + threadIdx.x;
  float4 v = *(const float4*)(cb + i4 * 4);
  ushort4 h4, l4;
  fsplit(v.x, h4.x, l4.x);
  fsplit(v.y, h4.y, l4.y);
  fsplit(v.z, h4.z, l4.z);
  fsplit(v.w, h4.w, l4.w);
  *(ushort4*)(hi + i4 * 4) = h4;
  *(ushort4*)(lo + i4 * 4) = l4;
}

// ---------------------------------------------------------------------------
// Codebook squared norms in f64 (one wave per code, all stages at once)
// ---------------------------------------------------------------------------
__global__ __launch_bounds__(256) void cnorm_kernel(
    const float* __restrict__ cb, double* __restrict__ cn) {
  const int w = blockIdx.x * 4 + (threadIdx.x >> 6);
  const int lane = threadIdx.x & 63;
  const float* row = cb + (size_t)w * HID;
  double s = 0.0;
  for (int h = lane; h < HID; h += 64) {
    double v = (double)row[h];
    s += v * v;
  }
#pragma unroll
  for (int off = 32; off > 0; off >>= 1) s += __shfl_down(s, off, 64);
  if (lane == 0) cn[w] = s;
}

// ---------------------------------------------------------------------------
// MFMA argmin (proven round-3 version). f64 epilogue:
// d = cn - 2*acch - (2/2048)*accc, compared in f64, tie-break smallest idx.
// ---------------------------------------------------------------------------
__global__ __launch_bounds__(256) void rvq_argmin_mfma(
    const u16* __restrict__ Ahi, const u16* __restrict__ Alo,
    const u16* __restrict__ Bhi, const u16* __restrict__ Blo,
    const double* __restrict__ cn, int* __restrict__ idxbuf,
    float* __restrict__ idxout) {
  __shared__ __attribute__((aligned(16))) u16 As[2 * 64 * 32];
  __shared__ __attribute__((aligned(16))) u16 Bs[2 * 128 * 32];
  __shared__ double mergeD[128];
  __shared__ int mergeI[128];

  const int tid = threadIdx.x;
  const int w = tid >> 6, l = tid & 63;
  const int wr = w >> 1, wc = w & 1;
  const int lr = l & 15, g = l >> 4;
  const int m0 = blockIdx.x * 64;

  double bestD[2][4];
  int bestI[2][4];
#pragma unroll
  for (int mr = 0; mr < 2; ++mr)
#pragma unroll
    for (int q = 0; q < 4; ++q) { bestD[mr][q] = 1e300; bestI[mr][q] = 0; }

  for (int chunk = 0; chunk < KCB / 128; ++chunk) {
    const int cbase = chunk * 128;
    f32x4 acch[2][4], accc[2][4];
#pragma unroll
    for (int mr = 0; mr < 2; ++mr)
#pragma unroll
      for (int nr = 0; nr < 4; ++nr) {
        acch[mr][nr] = (f32x4)0.0f;
        accc[mr][nr] = (f32x4)0.0f;
      }

    for (int ks = 0; ks < HID / 32; ++ks) {
      const int k0 = ks * 32;
      __syncthreads();
      stage16(Ahi, m0 + w * 16, w * 16, k0, As + w * 16 * 32, l, HID);
      stage16(Alo, m0 + w * 16, w * 16, k0, As + 2048 + w * 16 * 32, l, HID);
      stage16(Bhi, cbase + w * 16, w * 16, k0, Bs + w * 16 * 32, l, HID);
      stage16(Bhi, cbase + (w + 4) * 16, (w + 4) * 16, k0, Bs + (w + 4) * 16 * 32, l, HID);
      stage16(Blo, cbase + w * 16, w * 16, k0, Bs + 4096 + w * 16 * 32, l, HID);
      stage16(Blo, cbase + (w + 4) * 16, (w + 4) * 16, k0, Bs + 4096 + (w + 4) * 16 * 32, l, HID);
      __syncthreads();

      f16x8 ah[2], al[2], bh[4], bl[4];
#pragma unroll
      for (int mr = 0; mr < 2; ++mr) {
        const int ra = wr * 32 + mr * 16 + lr;
        const int pa = (g ^ SWZ(ra)) * 8;
        ah[mr] = *(const f16x8*)(As + ra * 32 + pa);
        al[mr] = *(const f16x8*)(As + 2048 + ra * 32 + pa);
      }
#pragma unroll
      for (int nr = 0; nr < 4; ++nr) {
        const int rb = wc * 64 + nr * 16 + lr;
        const int pb = (g ^ SWZ(rb)) * 8;
        bh[nr] = *(const f16x8*)(Bs + rb * 32 + pb);
        bl[nr] = *(const f16x8*)(Bs + 4096 + rb * 32 + pb);
      }
#pragma unroll
      for (int mr = 0; mr < 2; ++mr)
#pragma unroll
        for (int nr = 0; nr < 4; ++nr) {
          acch[mr][nr] = __builtin_amdgcn_mfma_f32_16x16x32_f16(
              ah[mr], bh[nr], acch[mr][nr], 0, 0, 0);
          accc[mr][nr] = __builtin_amdgcn_mfma_f32_16x16x32_f16(
              ah[mr], bl[nr], accc[mr][nr], 0, 0, 0);
          accc[mr][nr] = __builtin_amdgcn_mfma_f32_16x16x32_f16(
              al[mr], bh[nr], accc[mr][nr], 0, 0, 0);
        }
    }

#pragma unroll
    for (int nr = 0; nr < 4; ++nr) {
      const int code = cbase + wc * 64 + nr * 16 + lr;
      const double cnj = cn[code];
#pragma unroll
      for (int mr = 0; mr < 2; ++mr) {
#pragma unroll
        for (int q = 0; q < 4; ++q) {
          double d = cnj - 2.0 * (double)acch[mr][nr][q]
                         - 9.765625e-4 * (double)accc[mr][nr][q];
          if (d < bestD[mr][q]) { bestD[mr][q] = d; bestI[mr][q] = code; }
        }
      }
    }
  }

#pragma unroll
  for (int mr = 0; mr < 2; ++mr) {
#pragma unroll
    for (int q = 0; q < 4; ++q) {
      double d = bestD[mr][q];
      int i = bestI[mr][q];
#pragma unroll
      for (int off = 1; off < 16; off <<= 1) {
        double od = __shfl_xor(d, off, 64);
        int oi = __shfl_xor(i, off, 64);
        if (od < d || (od == d && oi < i)) { d = od; i = oi; }
      }
      if (lr == 0) {
        const int tl = wr * 32 + mr * 16 + 4 * g + q;
        mergeD[tl * 2 + wc] = d;
        mergeI[tl * 2 + wc] = i;
      }
    }
  }
  __syncthreads();
  if (tid < 64) {
    double d0 = mergeD[tid * 2], d1 = mergeD[tid * 2 + 1];
    int i0 = mergeI[tid * 2], i1 = mergeI[tid * 2 + 1];
    if (d1 < d0 || (d1 == d0 && i1 < i0)) { d0 = d1; i0 = i1; }
    idxbuf[m0 + tid] = i0;
    idxout[m0 + tid] = (float)i0;
  }
}

// ---------------------------------------------------------------------------
// Gather sel; quant += sel; resid(split) -= sel (or, LAST: splits <- quant).
// ---------------------------------------------------------------------------
template <bool LAST>
__global__ __launch_bounds__(256) void rvq_update(
    const float* __restrict__ cb, const int* __restrict__ idxbuf,
    float* __restrict__ quant, u16* __restrict__ rhi, u16* __restrict__ rlo) {
  const size_t gid = (size_t)blockIdx.x * blockDim.x + threadIdx.x;  // N_TOK*128
  const int t = (int)(gid >> 7);
  const int q4 = (int)(gid & 127);
  const int idx = idxbuf[t];
  const float4 c = *((const float4*)(cb + (size_t)idx * HID) + q4);
  float4* qp = (float4*)(quant + (size_t)t * HID) + q4;
  float4 qv = *qp;
  ushort4* hp = (ushort4*)(rhi + (size_t)t * HID) + q4;
  ushort4* lp = (ushort4*)(rlo + (size_t)t * HID) + q4;
  ushort4 h4 = *hp, l4 = *lp;
  float cc[4] = {c.x, c.y, c.z, c.w};
  u16 hs[4] = {h4.x, h4.y, h4.z, h4.w}, ls[4] = {l4.x, l4.y, l4.z, l4.w};
  float qn[4] = {qv.x + cc[0], qv.y + cc[1], qv.z + cc[2], qv.w + cc[3]};
#pragma unroll
  for (int j = 0; j < 4; ++j) {
    if (LAST) {
      fsplit(qn[j], hs[j], ls[j]);  // splits now hold quantized (decoder input)
    } else {
      float r = h_bits2f(hs[j]) + h_bits2f(ls[j]) * (1.0f / 2048.0f) - cc[j];
      fsplit(r, hs[j], ls[j]);
    }
  }
  qv.x = qn[0]; qv.y = qn[1]; qv.z = qn[2]; qv.w = qn[3];
  *qp = qv;
  h4.x = hs[0]; h4.y = hs[1]; h4.z = hs[2]; h4.w = hs[3];
  l4.x = ls[0]; l4.y = ls[1]; l4.z = ls[2]; l4.w = ls[3];
  *hp = h4;
  *lp = l4;
}

// ---------------------------------------------------------------------------
extern "C" void kernel_launch(void* const* d_in, const int* in_sizes, int n_in,
                              void* d_out, int out_size, void* d_ws, size_t ws_size,
                              hipStream_t stream) {
  const float* x      = (const float*)d_in[0];
  const float* enc_w1 = (const float*)d_in[1];
  const float* enc_b1 = (const float*)d_in[2];
  const float* enc_w2 = (const float*)d_in[3];
  const float* enc_b2 = (const float*)d_in[4];
  const float* dec_w1 = (const float*)d_in[5];
  const float* dec_b1 = (const float*)d_in[6];
  const float* dec_w2 = (const float*)d_in[7];
  const float* dec_b2 = (const float*)d_in[8];
  const float* cbs    = (const float*)d_in[9];

  float* quant  = (float*)d_out;                // [N_TOK, HID]
  float* idxout = quant + (size_t)N_TOK * HID;  // [NCB, N_TOK] as float
  float* recon  = idxout + (size_t)NCB * N_TOK; // [N_TOK, DIN]

  // workspace (~94.4 MB)
  char* wsp = (char*)d_ws;
  u16* rhi = (u16*)wsp;      wsp += (size_t)N_TOK * HID * 2;       // 33.55 MB
  u16* rlo = (u16*)wsp;      wsp += (size_t)N_TOK * HID * 2;       // 33.55 MB
  u16* whi = (u16*)wsp;      wsp += (size_t)2560 * 1024 * 2;       // 5.24 MB
  u16* wlo = (u16*)wsp;      wsp += (size_t)2560 * 1024 * 2;       // 5.24 MB
  char* h1region = wsp;      wsp += (size_t)CHUNK_E * H2 * 4;      // 16.78 MB
  int* idxbuf = (int*)wsp;   wsp += (size_t)NCB * N_TOK * 4;       // 0.39 MB
  double* cn = (double*)wsp; wsp += (size_t)NCB * KCB * 8;         // 0.10 MB

  // decoder weight-split offsets (elements, per plane)
  u16* dw1Thi = whi;              u16* dw1Tlo = wlo;              // [1024][512]
  u16* dw2Thi = whi + 524288;     u16* dw2Tlo = wlo + 524288;     // [1024][1024]

  float* h1f  = (float*)h1region;             // enc: [CHUNK_E][H2] f32
  u16*   h1hi = (u16*)h1region;               // dec: [CHUNK_D][H2] f16
  u16*   cbshi = (u16*)h1region;              // RVQ: stage cb splits (alias)
  u16*   cbslo = cbshi + (size_t)KCB * HID;

  wtsplit<<<dim3(H2 / 32, HID / 32), 256, 0, stream>>>(dec_w1, dw1Thi, dw1Tlo, HID, H2);
  wtsplit<<<dim3(DIN / 32, H2 / 32), 256, 0, stream>>>(dec_w2, dw2Thi, dw2Tlo, H2, DIN);
  cnorm_kernel<<<NCB * KCB / 4, 256, 0, stream>>>(cbs, cn);

  // encoder: fp32 (index-critical, r3-proven numerics)
  for (int c = 0; c < N_TOK / CHUNK_E; ++c) {
    gemm_bias<true, false><<<dim3(H2 / 64, CHUNK_E / 64), 256, 0, stream>>>(
        x + (size_t)c * CHUNK_E * DIN, enc_w1, enc_b1, h1f, nullptr, nullptr,
        CHUNK_E, DIN, H2);
    gemm_bias<false, true><<<dim3(HID / 64, CHUNK_E / 64), 256, 0, stream>>>(
        h1f, enc_w2, enc_b2, nullptr,
        rhi + (size_t)c * CHUNK_E * HID, rlo + (size_t)c * CHUNK_E * HID,
        CHUNK_E, H2, HID);
  }

  hipMemsetAsync(d_out, 0, (size_t)N_TOK * HID * 4, stream);

  // RVQ stages
  for (int s = 0; s < NCB; ++s) {
    const float* cb = cbs + (size_t)s * KCB * HID;
    cbsplit_kernel<<<(KCB * HID / 4) / 256, 256, 0, stream>>>(cb, cbshi, cbslo);
    rvq_argmin_mfma<<<N_TOK / 64, 256, 0, stream>>>(
        rhi, rlo, cbshi, cbslo, cn + (size_t)s * KCB,
        idxbuf + (size_t)s * N_TOK, idxout + (size_t)s * N_TOK);
    if (s < NCB - 1)
      rvq_update<false><<<(N_TOK * 128) / 256, 256, 0, stream>>>(
          cb, idxbuf + (size_t)s * N_TOK, quant, rhi, rlo);
    else
      rvq_update<true><<<(N_TOK * 128) / 256, 256, 0, stream>>>(
          cb, idxbuf + (size_t)s * N_TOK, quant, rhi, rlo);
  }

  // decoder: single-product f16 MFMA (recon tolerance ~100x margin)
  for (int c = 0; c < N_TOK / CHUNK_D; ++c) {
    gemm_mfma_f16<true, true><<<dim3(H2 / 128, CHUNK_D / 64), 256, 0, stream>>>(
        rhi + (size_t)c * CHUNK_D * HID, dw1Thi, dec_b1,
        nullptr, h1hi, CHUNK_D, HID, H2);
    gemm_mfma_f16<false, false><<<dim3(DIN / 128, CHUNK_D / 64), 256, 0, stream>>>(
        h1hi, dw2Thi, dec_b2,
        recon + (size_t)c * CHUNK_D * DIN, nullptr, CHUNK_D, H2, DIN);
  }
}